// Round 8
// baseline (343.666 us; speedup 1.0000x reference)
//
#include <hip/hip_runtime.h>

#define D 128
#define GSHIFT 8
#define NBUCKET 196           // ceil(N=50000 / 256) groups of 256 dst nodes
#define CHUNK 8192            // edges per sort block (R8: 4096 -> 8192)
#define NCHK 8                // chunk-parallelism for the block-prefix scans

typedef unsigned int uint;
typedef unsigned short ushort;
typedef unsigned long long ull;

typedef __attribute__((ext_vector_type(8))) short bf16x8;
typedef __attribute__((ext_vector_type(4))) float f32x4;

__device__ inline ushort f2bf(float f) {
    uint u = __float_as_uint(f);
    uint r = (u + 0x7fffu + ((u >> 16) & 1u)) >> 16;   // RNE
    return (ushort)r;
}

__device__ inline float bflo(uint g) { return __uint_as_float(g << 16); }
__device__ inline float bfhi(uint g) { return __uint_as_float(g & 0xffff0000u); }

// ============ CSR build: bucket sort on dst>>8; W->bf16 piggybacked ========

__global__ __launch_bounds__(256) void k_rhist(const int* __restrict__ col,
                                               int* __restrict__ ghist, int e,
                                               int nbSort,
                                               const float* __restrict__ W,
                                               ushort* __restrict__ Wb) {
    if (blockIdx.x >= nbSort) {
        int i = ((blockIdx.x - nbSort) * 256 + threadIdx.x) * 8;
        float4 a = *(const float4*)(W + i);
        float4 b = *(const float4*)(W + i + 4);
        ushort4 p, q;
        p.x = f2bf(a.x); p.y = f2bf(a.y); p.z = f2bf(a.z); p.w = f2bf(a.w);
        q.x = f2bf(b.x); q.y = f2bf(b.y); q.z = f2bf(b.z); q.w = f2bf(b.w);
        *(ushort4*)(Wb + i) = p;
        *(ushort4*)(Wb + i + 4) = q;
        return;
    }
    __shared__ int hist[NBUCKET];
    int t = threadIdx.x;
    if (t < NBUCKET) hist[t] = 0;
    __syncthreads();
    int i0 = blockIdx.x * CHUNK;
    int i1 = min(i0 + CHUNK, e);
    for (int i = i0 + t; i < i1; i += 256)
        atomicAdd(&hist[col[i] >> GSHIFT], 1);
    __syncthreads();
    if (t < NBUCKET) ghist[(size_t)blockIdx.x * NBUCKET + t] = hist[t];
}

__global__ __launch_bounds__(256) void k_rscanA(const int* __restrict__ ghist,
                                                int* __restrict__ cpart, int nb) {
    int c = blockIdx.x;
    int t = threadIdx.x;
    if (t >= NBUCKET) return;
    int clen = (nb + NCHK - 1) / NCHK;
    int b0 = c * clen, b1 = min(b0 + clen, nb);
    int s = 0;
    int b = b0;
    for (; b + 3 < b1; b += 4) {
        const int* p = ghist + (size_t)b * NBUCKET + t;
        int v0 = p[0];
        int v1 = p[NBUCKET];
        int v2 = p[2 * NBUCKET];
        int v3 = p[3 * NBUCKET];
        s += (v0 + v1) + (v2 + v3);
    }
    for (; b < b1; ++b) s += ghist[(size_t)b * NBUCKET + t];
    cpart[c * NBUCKET + t] = s;
}

__global__ __launch_bounds__(256) void k_rscanB(int* __restrict__ cpart,
                                                int* __restrict__ gptr,
                                                int* __restrict__ ptr, int n, int e) {
    int t = threadIdx.x;
    int lane = t & 63, wid = t >> 6;
    int v[NCHK];
    int tot = 0;
#pragma unroll
    for (int c = 0; c < NCHK; ++c) {
        v[c] = (t < NBUCKET) ? cpart[c * NBUCKET + t] : 0;
        tot += v[c];
    }
    int s = tot;
#pragma unroll
    for (int off = 1; off < 64; off <<= 1) {
        int u = __shfl_up(s, off);
        if (lane >= off) s += u;
    }
    __shared__ int wsum[4];
    if (lane == 63) wsum[wid] = s;
    __syncthreads();
    int wo = 0;
    for (int w2 = 0; w2 < wid; ++w2) wo += wsum[w2];
    s += wo;
    int run = s - tot;
    if (t < NBUCKET) {
        gptr[t] = run;
        int rc = run;
#pragma unroll
        for (int c = 0; c < NCHK; ++c) { cpart[c * NBUCKET + t] = rc; rc += v[c]; }
    }
    if (t == 255) { gptr[NBUCKET] = e; ptr[n] = e; }
}

__global__ __launch_bounds__(256) void k_rscanC(const int* __restrict__ cpart,
                                                int* __restrict__ ghist, int nb) {
    int c = blockIdx.x;
    int t = threadIdx.x;
    if (t >= NBUCKET) return;
    int clen = (nb + NCHK - 1) / NCHK;
    int b0 = c * clen, b1 = min(b0 + clen, nb);
    int run = cpart[c * NBUCKET + t];
    int b = b0;
    for (; b + 3 < b1; b += 4) {
        int* p = ghist + (size_t)b * NBUCKET + t;
        int v0 = p[0];
        int v1 = p[NBUCKET];
        int v2 = p[2 * NBUCKET];
        int v3 = p[3 * NBUCKET];
        p[0] = run;           run += v0;
        p[NBUCKET] = run;     run += v1;
        p[2 * NBUCKET] = run; run += v2;
        p[3 * NBUCKET] = run; run += v3;
    }
    for (; b < b1; ++b) {
        size_t idx = (size_t)b * NBUCKET + t;
        int vv = ghist[idx];
        ghist[idx] = run;
        run += vv;
    }
}

__global__ __launch_bounds__(256) void k_rscatter(const int* __restrict__ row,
                                                  const int* __restrict__ col,
                                                  const float* __restrict__ w,
                                                  const int* __restrict__ ghist,
                                                  ull* __restrict__ rec, int e) {
    __shared__ int cur[NBUCKET];
    int t = threadIdx.x;
    if (t < NBUCKET) cur[t] = ghist[(size_t)blockIdx.x * NBUCKET + t];
    __syncthreads();
    int i0 = blockIdx.x * CHUNK;
    int i1 = min(i0 + CHUNK, e);
    for (int i = i0 + t; i < i1; i += 256) {
        int dst = col[i];
        int src = row[i];
        uint wb = __float_as_uint(w[i]);
        int pos = atomicAdd(&cur[dst >> GSHIFT], 1);
        rec[pos] = ((ull)(uint)dst << 48) | ((ull)(uint)src << 32) | (ull)wb;
    }
}

__global__ __launch_bounds__(256) void k_finish(const ull* __restrict__ rec,
                                                const int* __restrict__ gptr,
                                                int* __restrict__ ptr,
                                                float* __restrict__ dinv,
                                                int2* __restrict__ csr, int n) {
    __shared__ int   cnt[256];
    __shared__ float wsf[256];
    __shared__ int   cur[256];
    __shared__ int   bsum[4];
    int g = blockIdx.x;
    int t = threadIdx.x;
    int lo = gptr[g], hi = gptr[g + 1];
    cnt[t] = 0;
    wsf[t] = 0.0f;
    __syncthreads();
    for (int i = lo + t; i < hi; i += 256) {
        ull r = rec[i];
        int d8 = (int)((r >> 48) & 255);
        atomicAdd(&cnt[d8], 1);
        atomicAdd(&wsf[d8], __uint_as_float((uint)r));
    }
    __syncthreads();
    int c = cnt[t];
    int lane = t & 63, wid = t >> 6;
    int s = c;
#pragma unroll
    for (int off = 1; off < 64; off <<= 1) {
        int u = __shfl_up(s, off);
        if (lane >= off) s += u;
    }
    if (lane == 63) bsum[wid] = s;
    __syncthreads();
    int wo = 0;
    for (int w2 = 0; w2 < wid; ++w2) wo += bsum[w2];
    int beg = lo + wo + s - c;
    int node = (g << GSHIFT) + t;
    if (node < n) {
        ptr[node] = beg;
        dinv[node] = rsqrtf(fmaxf(1.0f + wsf[t], 1e-12f));
    }
    cur[t] = beg;
    __syncthreads();
    for (int i = lo + t; i < hi; i += 256) {
        ull r = rec[i];
        int d8 = (int)((r >> 48) & 255);
        int pos = atomicAdd(&cur[d8], 1);
        csr[pos] = make_int2((int)((r >> 32) & 0xffff), (int)(uint)r);
    }
}

// ---------------- layer-0 MFMA GEMM (f32 input only) -----------------------

#define LDW 136

__global__ __launch_bounds__(256) void k_gemm0(const float* __restrict__ hf,
                                               const ushort* __restrict__ Wb,
                                               const float* __restrict__ dinv,
                                               ushort* __restrict__ xw, int n) {
    __shared__ ushort Hl[64 * LDW];
    __shared__ float  sdv[64];

    const int t   = threadIdx.x;
    const int gn0 = blockIdx.x * 64;

    if (t < 64) {
        int gn = gn0 + t;
        sdv[t] = (gn < n) ? dinv[gn] : 0.0f;
    }
    for (int i = t; i < 2048; i += 256) {
        int r  = i >> 5;
        int k4 = (i & 31) * 4;
        int gn = gn0 + r;
        float4 hv = (gn < n) ? *(const float4*)(hf + (size_t)gn * D + k4)
                             : make_float4(0.f, 0.f, 0.f, 0.f);
        ushort4 p;
        p.x = f2bf(hv.x); p.y = f2bf(hv.y); p.z = f2bf(hv.z); p.w = f2bf(hv.w);
        *(ushort4*)(Hl + r * LDW + k4) = p;
    }
    __syncthreads();

    const int wave  = t >> 6;
    const int lane  = t & 63;
    const int quad  = lane >> 4;
    const int l15   = lane & 15;
    const int nbase = wave * 32;

    f32x4 acc[4][2];
#pragma unroll
    for (int mt = 0; mt < 4; ++mt)
#pragma unroll
        for (int nt = 0; nt < 2; ++nt) acc[mt][nt] = (f32x4)(0.0f);

#pragma unroll
    for (int kc = 0; kc < 4; ++kc) {
        int ko = kc * 32 + quad * 8;
        bf16x8 a[4], b[2];
#pragma unroll
        for (int nt = 0; nt < 2; ++nt)
            b[nt] = *(const bf16x8*)(Wb + (size_t)(nbase + nt * 16 + l15) * D + ko);
#pragma unroll
        for (int mt = 0; mt < 4; ++mt)
            a[mt] = *(const bf16x8*)(Hl + (mt * 16 + l15) * LDW + ko);
#pragma unroll
        for (int mt = 0; mt < 4; ++mt)
#pragma unroll
            for (int nt = 0; nt < 2; ++nt)
                acc[mt][nt] = __builtin_amdgcn_mfma_f32_16x16x32_bf16(
                    a[mt], b[nt], acc[mt][nt], 0, 0, 0);
    }
    __syncthreads();

#pragma unroll
    for (int mt = 0; mt < 4; ++mt)
#pragma unroll
        for (int r = 0; r < 4; ++r) {
            int rowl = mt * 16 + quad * 4 + r;
            float dv = sdv[rowl];
#pragma unroll
            for (int nt = 0; nt < 2; ++nt)
                Hl[rowl * LDW + nbase + nt * 16 + l15] = f2bf(acc[mt][nt][r] * dv);
        }
    __syncthreads();

    for (int i = t; i < 1024; i += 256) {
        int r = i >> 4, seg = i & 15;
        int gn = gn0 + r;
        if (gn < n) {
            uint4 v = *(const uint4*)(Hl + r * LDW + seg * 8);
            *(uint4*)(xw + (size_t)gn * D + seg * 8) = v;
        }
    }
}

// ------- fused pull + bias + LN + ReLU + residual (+ next-layer GEMM) -------
// 16 lanes/node x 16 nodes/block. 8-deep edge unroll (8 uint4 gathers in
// flight per lane) to halve the serial gather chain. Fused epilogue writes
// MFMA output to a separate LDS buffer (Ol) — one fewer barrier.

template <int ID_BF16, int OUT_BF16, int FUSE>
__global__ __launch_bounds__(256) void k_pull_ln(const ushort* __restrict__ xw,
                                                 const int* __restrict__ ptr,
                                                 const int2* __restrict__ csr,
                                                 const float* __restrict__ dinv,
                                                 const float* __restrict__ bias,
                                                 const float* __restrict__ gamma,
                                                 const float* __restrict__ beta,
                                                 const void* __restrict__ identity,
                                                 void* __restrict__ hout,
                                                 const ushort* __restrict__ Wn,
                                                 ushort* __restrict__ xwout,
                                                 int n, int relu) {
    __shared__ ushort Hl[16 * LDW];
    __shared__ ushort Ol[16 * LDW];
    __shared__ float  sdv[16];

    const int t     = threadIdx.x;
    const int node0 = blockIdx.x * 16;
    const int g16   = t >> 4;          // node slot 0..15
    const int f     = t & 15;          // feature group
    const int o     = f * 8;           // 8 bf16 features = 16B
    const int node  = node0 + g16;
    const bool act  = node < n;

    float a0 = 0.f, a1 = 0.f, a2 = 0.f, a3 = 0.f;
    float a4 = 0.f, a5 = 0.f, a6 = 0.f, a7 = 0.f;

    int ebeg = act ? ptr[node] : 0;
    int eend = act ? ptr[node + 1] : 0;

#define ACC8(nw, g)                                        \
    a0 += nw * bflo(g.x); a1 += nw * bfhi(g.x);            \
    a2 += nw * bflo(g.y); a3 += nw * bfhi(g.y);            \
    a4 += nw * bflo(g.z); a5 += nw * bfhi(g.z);            \
    a6 += nw * bflo(g.w); a7 += nw * bfhi(g.w);

    int e = ebeg;
    for (; e + 7 < eend; e += 8) {
        int2 c0 = csr[e],     c1 = csr[e + 1], c2 = csr[e + 2], c3 = csr[e + 3];
        int2 c4 = csr[e + 4], c5 = csr[e + 5], c6 = csr[e + 6], c7 = csr[e + 7];
        uint4 g0 = *(const uint4*)(xw + (size_t)c0.x * D + o);
        uint4 g1 = *(const uint4*)(xw + (size_t)c1.x * D + o);
        uint4 g2 = *(const uint4*)(xw + (size_t)c2.x * D + o);
        uint4 g3 = *(const uint4*)(xw + (size_t)c3.x * D + o);
        uint4 g4 = *(const uint4*)(xw + (size_t)c4.x * D + o);
        uint4 g5 = *(const uint4*)(xw + (size_t)c5.x * D + o);
        uint4 g6 = *(const uint4*)(xw + (size_t)c6.x * D + o);
        uint4 g7 = *(const uint4*)(xw + (size_t)c7.x * D + o);
        float n0 = __int_as_float(c0.y), n1 = __int_as_float(c1.y);
        float n2 = __int_as_float(c2.y), n3 = __int_as_float(c3.y);
        float n4 = __int_as_float(c4.y), n5 = __int_as_float(c5.y);
        float n6 = __int_as_float(c6.y), n7 = __int_as_float(c7.y);
        ACC8(n0, g0)
        ACC8(n1, g1)
        ACC8(n2, g2)
        ACC8(n3, g3)
        ACC8(n4, g4)
        ACC8(n5, g5)
        ACC8(n6, g6)
        ACC8(n7, g7)
    }
    for (; e + 3 < eend; e += 4) {
        int2 c0 = csr[e], c1 = csr[e + 1], c2 = csr[e + 2], c3 = csr[e + 3];
        uint4 g0 = *(const uint4*)(xw + (size_t)c0.x * D + o);
        uint4 g1 = *(const uint4*)(xw + (size_t)c1.x * D + o);
        uint4 g2 = *(const uint4*)(xw + (size_t)c2.x * D + o);
        uint4 g3 = *(const uint4*)(xw + (size_t)c3.x * D + o);
        float n0 = __int_as_float(c0.y), n1 = __int_as_float(c1.y);
        float n2 = __int_as_float(c2.y), n3 = __int_as_float(c3.y);
        ACC8(n0, g0)
        ACC8(n1, g1)
        ACC8(n2, g2)
        ACC8(n3, g3)
    }
    for (; e < eend; ++e) {
        int2 c0 = csr[e];
        uint4 g0 = *(const uint4*)(xw + (size_t)c0.x * D + o);
        float n0 = __int_as_float(c0.y);
        ACC8(n0, g0)
    }
#undef ACC8

    float o0 = 0.f, o1 = 0.f, o2 = 0.f, o3 = 0.f;
    float o4 = 0.f, o5 = 0.f, o6 = 0.f, o7 = 0.f;
    float di = 0.f;
    if (act) {
        di = dinv[node];
        uint4 ps = *(const uint4*)(xw + (size_t)node * D + o);
        float4 bbA = *(const float4*)(bias + o);
        float4 bbB = *(const float4*)(bias + o + 4);
        a0 = bbA.x + di * (bflo(ps.x) + a0);
        a1 = bbA.y + di * (bfhi(ps.x) + a1);
        a2 = bbA.z + di * (bflo(ps.y) + a2);
        a3 = bbA.w + di * (bfhi(ps.y) + a3);
        a4 = bbB.x + di * (bflo(ps.z) + a4);
        a5 = bbB.y + di * (bfhi(ps.z) + a5);
        a6 = bbB.z + di * (bflo(ps.w) + a6);
        a7 = bbB.w + di * (bfhi(ps.w) + a7);

        // LayerNorm over 128 features: reduce across the node's 16 lanes
        float s = ((a0 + a1) + (a2 + a3)) + ((a4 + a5) + (a6 + a7));
#pragma unroll
        for (int off = 8; off; off >>= 1) s += __shfl_xor(s, off);
        float mu = s * (1.0f / 128.0f);
        float d0 = a0 - mu, d1 = a1 - mu, d2 = a2 - mu, d3 = a3 - mu;
        float d4 = a4 - mu, d5 = a5 - mu, d6 = a6 - mu, d7 = a7 - mu;
        float vs = ((d0 * d0 + d1 * d1) + (d2 * d2 + d3 * d3))
                 + ((d4 * d4 + d5 * d5) + (d6 * d6 + d7 * d7));
#pragma unroll
        for (int off = 8; off; off >>= 1) vs += __shfl_xor(vs, off);
        float rs = rsqrtf(vs * (1.0f / 128.0f) + 1e-5f);

        float4 gA  = *(const float4*)(gamma + o);
        float4 gB  = *(const float4*)(gamma + o + 4);
        float4 b2A = *(const float4*)(beta + o);
        float4 b2B = *(const float4*)(beta + o + 4);
        float i0, i1, i2, i3, i4, i5, i6, i7;
        if (ID_BF16) {
            uint4 iv = *(const uint4*)((const ushort*)identity + (size_t)node * D + o);
            i0 = bflo(iv.x); i1 = bfhi(iv.x); i2 = bflo(iv.y); i3 = bfhi(iv.y);
            i4 = bflo(iv.z); i5 = bfhi(iv.z); i6 = bflo(iv.w); i7 = bfhi(iv.w);
        } else {
            float4 ivA = *(const float4*)((const float*)identity + (size_t)node * D + o);
            float4 ivB = *(const float4*)((const float*)identity + (size_t)node * D + o + 4);
            i0 = ivA.x; i1 = ivA.y; i2 = ivA.z; i3 = ivA.w;
            i4 = ivB.x; i5 = ivB.y; i6 = ivB.z; i7 = ivB.w;
        }
        o0 = d0 * rs * gA.x + b2A.x;
        o1 = d1 * rs * gA.y + b2A.y;
        o2 = d2 * rs * gA.z + b2A.z;
        o3 = d3 * rs * gA.w + b2A.w;
        o4 = d4 * rs * gB.x + b2B.x;
        o5 = d5 * rs * gB.y + b2B.y;
        o6 = d6 * rs * gB.z + b2B.z;
        o7 = d7 * rs * gB.w + b2B.w;
        if (relu) {
            o0 = fmaxf(o0, 0.0f); o1 = fmaxf(o1, 0.0f);
            o2 = fmaxf(o2, 0.0f); o3 = fmaxf(o3, 0.0f);
            o4 = fmaxf(o4, 0.0f); o5 = fmaxf(o5, 0.0f);
            o6 = fmaxf(o6, 0.0f); o7 = fmaxf(o7, 0.0f);
        }
        o0 += i0; o1 += i1; o2 += i2; o3 += i3;
        o4 += i4; o5 += i5; o6 += i6; o7 += i7;

        uint4 pv;
        pv.x = (uint)f2bf(o0) | ((uint)f2bf(o1) << 16);
        pv.y = (uint)f2bf(o2) | ((uint)f2bf(o3) << 16);
        pv.z = (uint)f2bf(o4) | ((uint)f2bf(o5) << 16);
        pv.w = (uint)f2bf(o6) | ((uint)f2bf(o7) << 16);
        if (OUT_BF16) {
            *(uint4*)((ushort*)hout + (size_t)node * D + o) = pv;
        } else {
            float* hp = (float*)hout + (size_t)node * D + o;
            *(float4*)hp       = make_float4(o0, o1, o2, o3);
            *(float4*)(hp + 4) = make_float4(o4, o5, o6, o7);
        }
        if (FUSE) {
            *(uint4*)(Hl + g16 * LDW + o) = pv;
            if (f == 0) sdv[g16] = di;
        }
    } else if (FUSE) {
        uint4 z = make_uint4(0u, 0u, 0u, 0u);
        *(uint4*)(Hl + g16 * LDW + o) = z;
        if (f == 0) sdv[g16] = 0.0f;
    }

    if (FUSE) {
        __syncthreads();
        const int lane = t & 63, wv = t >> 6;
        const int l15 = lane & 15, quad = lane >> 4;
        const int nbase = wv * 32;
        f32x4 acc2[2];
        acc2[0] = (f32x4)(0.0f);
        acc2[1] = (f32x4)(0.0f);
#pragma unroll
        for (int kc = 0; kc < 4; ++kc) {
            int ko = kc * 32 + quad * 8;
            bf16x8 a  = *(const bf16x8*)(Hl + l15 * LDW + ko);
            bf16x8 b0 = *(const bf16x8*)(Wn + (size_t)(nbase + l15) * D + ko);
            bf16x8 b1 = *(const bf16x8*)(Wn + (size_t)(nbase + 16 + l15) * D + ko);
            acc2[0] = __builtin_amdgcn_mfma_f32_16x16x32_bf16(a, b0, acc2[0], 0, 0, 0);
            acc2[1] = __builtin_amdgcn_mfma_f32_16x16x32_bf16(a, b1, acc2[1], 0, 0, 0);
        }
        // write to separate LDS buffer: no barrier needed before this
#pragma unroll
        for (int r = 0; r < 4; ++r) {
            float dv = sdv[quad * 4 + r];
            Ol[(quad * 4 + r) * LDW + nbase + l15]      = f2bf(acc2[0][r] * dv);
            Ol[(quad * 4 + r) * LDW + nbase + 16 + l15] = f2bf(acc2[1][r] * dv);
        }
        __syncthreads();
        int row = t >> 4, seg = t & 15;
        int gn = node0 + row;
        if (gn < n) {
            *(uint4*)(xwout + (size_t)gn * D + seg * 8) =
                *(const uint4*)(Ol + row * LDW + seg * 8);
        }
    }
}

// ---------------- launch ----------------

extern "C" void kernel_launch(void* const* d_in, const int* in_sizes, int n_in,
                              void* d_out, int out_size, void* d_ws, size_t ws_size,
                              hipStream_t stream) {
    const float* x      = (const float*)d_in[0];
    const int*   ei     = (const int*)d_in[1];
    const float* ew     = (const float*)d_in[2];
    const float* Ws     = (const float*)d_in[3];
    const float* bs     = (const float*)d_in[4];
    const float* gammas = (const float*)d_in[5];
    const float* betas  = (const float*)d_in[6];
    float* out = (float*)d_out;

    const int N = in_sizes[0] / D;
    const int E = in_sizes[2];
    const int* row = ei;
    const int* col = ei + E;

    const int nbSort = (E + CHUNK - 1) / CHUNK;

    // workspace layout. recA (8B*E = 12.8MB) aliases the hb1/hb2/xwB union
    // (38.4MB): recA is dead after k_finish, before any of them is written.
    char* w8 = (char*)d_ws;
    ushort* Wb  = (ushort*)w8;  w8 += sizeof(ushort) * 3 * D * D;
    ushort* xwA = (ushort*)w8;  w8 += sizeof(ushort) * (size_t)N * D;  // layers 0,2
    size_t third = sizeof(ushort) * (size_t)N * D;                     // 12.8MB
    size_t unionBytes = 3 * third;                                     // hb1+hb2+xwB
    if (sizeof(ull) * (size_t)E > unionBytes) unionBytes = sizeof(ull) * (size_t)E;
    ull*    recA = (ull*)w8;
    ushort* hb1  = (ushort*)w8;
    ushort* hb2  = (ushort*)(w8 + third);
    ushort* xwB  = (ushort*)(w8 + 2 * third);                          // layer 1
    w8 += unionBytes;
    int2*  csr   = (int2*)w8;   w8 += sizeof(int2) * (size_t)E;
    int*   ghist = (int*)w8;    w8 += sizeof(int) * (size_t)nbSort * NBUCKET;
    int*   cpart = (int*)w8;    w8 += sizeof(int) * NCHK * NBUCKET;
    int*   gptr  = (int*)w8;    w8 += sizeof(int) * (NBUCKET + 4);
    int*   ptr   = (int*)w8;    w8 += sizeof(int) * (N + 4);
    float* dinv  = (float*)w8;  w8 += sizeof(float) * (size_t)N;

    dim3 blk(256);
    int gGemm = (N + 63) / 64;
    int gPull = (N + 15) / 16;
    int gWconv = (3 * D * D) / (256 * 8);      // 24

    k_rhist<<<nbSort + gWconv, blk, 0, stream>>>(col, ghist, E, nbSort, Ws, Wb);
    k_rscanA<<<NCHK, blk, 0, stream>>>(ghist, cpart, nbSort);
    k_rscanB<<<1, blk, 0, stream>>>(cpart, gptr, ptr, N, E);
    k_rscanC<<<NCHK, blk, 0, stream>>>(cpart, ghist, nbSort);
    k_rscatter<<<nbSort, blk, 0, stream>>>(row, col, ew, ghist, recA, E);
    k_finish<<<NBUCKET, blk, 0, stream>>>(recA, gptr, ptr, dinv, csr, N);

    // layer 0: xwA = dinv * x@W0^T
    k_gemm0<<<gGemm, blk, 0, stream>>>(x, Wb, dinv, xwA, N);
    // pull 0: h0 -> hb1; fused gemm: xwB = dinv * h0@W1^T
    k_pull_ln<0, 1, 1><<<gPull, blk, 0, stream>>>(xwA, ptr, csr, dinv,
                                                  bs, gammas, betas, x, hb1,
                                                  Wb + 16384, xwB, N, 1);
    // pull 1: h1 -> hb2; fused gemm: xwA = dinv * h1@W2^T
    k_pull_ln<1, 1, 1><<<gPull, blk, 0, stream>>>(xwB, ptr, csr, dinv,
                                                  bs + D, gammas + D, betas + D,
                                                  hb1, hb2,
                                                  Wb + 32768, xwA, N, 1);
    // pull 2: final -> out (f32), no fusion
    k_pull_ln<1, 0, 0><<<gPull, blk, 0, stream>>>(xwA, ptr, csr, dinv,
                                                  bs + 2 * D, gammas + 2 * D,
                                                  betas + 2 * D,
                                                  hb2, out,
                                                  (const ushort*)nullptr,
                                                  (ushort*)nullptr, N, 0);
}

// Round 9
// 328.013 us; speedup vs baseline: 1.0477x; 1.0477x over previous
//
#include <hip/hip_runtime.h>

#define D 128
#define GSHIFT 8
#define NBUCKET 196           // ceil(N=50000 / 256) groups of 256 dst nodes
#define CHUNK 8192            // edges per sort block
#define NCHK 16               // chunk-parallelism for the block-prefix scans

typedef unsigned int uint;
typedef unsigned short ushort;
typedef unsigned long long ull;

typedef __attribute__((ext_vector_type(8))) short bf16x8;
typedef __attribute__((ext_vector_type(4))) float f32x4;

__device__ inline ushort f2bf(float f) {
    uint u = __float_as_uint(f);
    uint r = (u + 0x7fffu + ((u >> 16) & 1u)) >> 16;   // RNE
    return (ushort)r;
}

__device__ inline float bflo(uint g) { return __uint_as_float(g << 16); }
__device__ inline float bfhi(uint g) { return __uint_as_float(g & 0xffff0000u); }

// ============ CSR build: bucket sort on dst>>8; W->bf16 piggybacked ========
// Heavy build kernels run 1024 threads/block: 196-block grids give only
// 1 block/CU, so 256-thread blocks = 4 waves/CU (12.5% occupancy) — the
// build was latency-starved, not work-bound.

__global__ __launch_bounds__(1024) void k_rhist(const int* __restrict__ col,
                                                int* __restrict__ ghist, int e,
                                                int nbSort,
                                                const float* __restrict__ W,
                                                ushort* __restrict__ Wb) {
    int t = threadIdx.x;
    if (blockIdx.x >= nbSort) {
        // piggybacked one-time W -> bf16 (3*128*128 = 6 blocks * 8192 elems)
        int i = ((blockIdx.x - nbSort) * 1024 + t) * 8;
        float4 a = *(const float4*)(W + i);
        float4 b = *(const float4*)(W + i + 4);
        ushort4 p, q;
        p.x = f2bf(a.x); p.y = f2bf(a.y); p.z = f2bf(a.z); p.w = f2bf(a.w);
        q.x = f2bf(b.x); q.y = f2bf(b.y); q.z = f2bf(b.z); q.w = f2bf(b.w);
        *(ushort4*)(Wb + i) = p;
        *(ushort4*)(Wb + i + 4) = q;
        return;
    }
    __shared__ int hist[NBUCKET];
    if (t < NBUCKET) hist[t] = 0;
    __syncthreads();
    int i0 = blockIdx.x * CHUNK;
    int i1 = min(i0 + CHUNK, e);
    for (int i = i0 + t; i < i1; i += 1024)
        atomicAdd(&hist[col[i] >> GSHIFT], 1);
    __syncthreads();
    if (t < NBUCKET) ghist[(size_t)blockIdx.x * NBUCKET + t] = hist[t];
}

// per-(chunk,digit) partial totals: block c sums its ~13 sort-blocks
__global__ __launch_bounds__(256) void k_rscanA(const int* __restrict__ ghist,
                                                int* __restrict__ cpart, int nb) {
    int c = blockIdx.x;
    int t = threadIdx.x;
    if (t >= NBUCKET) return;
    int clen = (nb + NCHK - 1) / NCHK;
    int b0 = c * clen, b1 = min(b0 + clen, nb);
    int s = 0;
    int b = b0;
    for (; b + 3 < b1; b += 4) {
        const int* p = ghist + (size_t)b * NBUCKET + t;
        int v0 = p[0];
        int v1 = p[NBUCKET];
        int v2 = p[2 * NBUCKET];
        int v3 = p[3 * NBUCKET];
        s += (v0 + v1) + (v2 + v3);
    }
    for (; b < b1; ++b) s += ghist[(size_t)b * NBUCKET + t];
    cpart[c * NBUCKET + t] = s;
}

// merged scanB+scanC: every block redundantly computes the 196-digit
// exclusive scan from cpart (registers), then rewrites its chunk's ghist
// to scatter bases. Block 0 also emits gptr / ptr[n].
__global__ __launch_bounds__(256) void k_rscanBC(const int* __restrict__ cpart,
                                                 int* __restrict__ ghist,
                                                 int* __restrict__ gptr,
                                                 int* __restrict__ ptr,
                                                 int n, int e, int nb) {
    int t = threadIdx.x;
    int cb = blockIdx.x;
    int lane = t & 63, wid = t >> 6;
    int v[NCHK];
    int tot = 0;
#pragma unroll
    for (int c = 0; c < NCHK; ++c) {
        v[c] = (t < NBUCKET) ? cpart[c * NBUCKET + t] : 0;
        tot += v[c];
    }
    int s = tot;
#pragma unroll
    for (int off = 1; off < 64; off <<= 1) {
        int u = __shfl_up(s, off);
        if (lane >= off) s += u;
    }
    __shared__ int wsum[4];
    if (lane == 63) wsum[wid] = s;
    __syncthreads();
    int wo = 0;
    for (int w2 = 0; w2 < wid; ++w2) wo += wsum[w2];
    s += wo;
    int run = s - tot;           // exclusive digit prefix = gptr[t]
    if (cb == 0) {
        if (t < NBUCKET) gptr[t] = run;
        if (t == 0) { gptr[NBUCKET] = e; ptr[n] = e; }
    }
    if (t >= NBUCKET) return;
    int base = run;
#pragma unroll
    for (int c = 0; c < NCHK; ++c) base += (c < cb) ? v[c] : 0;
    int clen = (nb + NCHK - 1) / NCHK;
    int b0 = cb * clen, b1 = min(b0 + clen, nb);
    for (int b = b0; b < b1; ++b) {
        size_t idx = (size_t)b * NBUCKET + t;
        int vv = ghist[idx];
        ghist[idx] = base;
        base += vv;
    }
}

__global__ __launch_bounds__(1024) void k_rscatter(const int* __restrict__ row,
                                                   const int* __restrict__ col,
                                                   const float* __restrict__ w,
                                                   const int* __restrict__ ghist,
                                                   ull* __restrict__ rec, int e) {
    __shared__ int cur[NBUCKET];
    int t = threadIdx.x;
    if (t < NBUCKET) cur[t] = ghist[(size_t)blockIdx.x * NBUCKET + t];
    __syncthreads();
    int i0 = blockIdx.x * CHUNK;
    int i1 = min(i0 + CHUNK, e);
    for (int i = i0 + t; i < i1; i += 1024) {
        int dst = col[i];
        int src = row[i];
        uint wb = __float_as_uint(w[i]);
        int pos = atomicAdd(&cur[dst >> GSHIFT], 1);
        rec[pos] = ((ull)(uint)dst << 48) | ((ull)(uint)src << 32) | (ull)wb;
    }
}

__global__ __launch_bounds__(1024) void k_finish(const ull* __restrict__ rec,
                                                 const int* __restrict__ gptr,
                                                 int* __restrict__ ptr,
                                                 float* __restrict__ dinv,
                                                 int2* __restrict__ csr, int n) {
    __shared__ int   cnt[256];
    __shared__ float wsf[256];
    __shared__ int   cur[256];
    __shared__ int   bsum[4];
    int g = blockIdx.x;
    int t = threadIdx.x;
    int lo = gptr[g], hi = gptr[g + 1];
    if (t < 256) { cnt[t] = 0; wsf[t] = 0.0f; }
    __syncthreads();
    for (int i = lo + t; i < hi; i += 1024) {
        ull r = rec[i];
        int d8 = (int)((r >> 48) & 255);
        atomicAdd(&cnt[d8], 1);
        atomicAdd(&wsf[d8], __uint_as_float((uint)r));
    }
    __syncthreads();
    int s = 0, c = 0;
    int lane = t & 63, wid = t >> 6;
    if (t < 256) {                       // waves 0-3 only: wave-uniform branch
        c = cnt[t];
        s = c;
#pragma unroll
        for (int off = 1; off < 64; off <<= 1) {
            int u = __shfl_up(s, off);
            if (lane >= off) s += u;
        }
        if (lane == 63) bsum[wid] = s;
    }
    __syncthreads();
    if (t < 256) {
        int wo = 0;
        for (int w2 = 0; w2 < wid; ++w2) wo += bsum[w2];
        int beg = lo + wo + s - c;       // exclusive prefix
        int node = (g << GSHIFT) + t;
        if (node < n) {
            ptr[node] = beg;
            dinv[node] = rsqrtf(fmaxf(1.0f + wsf[t], 1e-12f));
        }
        cur[t] = beg;
    }
    __syncthreads();
    for (int i = lo + t; i < hi; i += 1024) {
        ull r = rec[i];
        int d8 = (int)((r >> 48) & 255);
        int pos = atomicAdd(&cur[d8], 1);
        csr[pos] = make_int2((int)((r >> 32) & 0xffff), (int)(uint)r);
    }
}

// ---------------- layer-0 MFMA GEMM (f32 input only) -----------------------

#define LDW 136

__global__ __launch_bounds__(256) void k_gemm0(const float* __restrict__ hf,
                                               const ushort* __restrict__ Wb,
                                               const float* __restrict__ dinv,
                                               ushort* __restrict__ xw, int n) {
    __shared__ ushort Hl[64 * LDW];
    __shared__ float  sdv[64];

    const int t   = threadIdx.x;
    const int gn0 = blockIdx.x * 64;

    if (t < 64) {
        int gn = gn0 + t;
        sdv[t] = (gn < n) ? dinv[gn] : 0.0f;
    }
    for (int i = t; i < 2048; i += 256) {
        int r  = i >> 5;
        int k4 = (i & 31) * 4;
        int gn = gn0 + r;
        float4 hv = (gn < n) ? *(const float4*)(hf + (size_t)gn * D + k4)
                             : make_float4(0.f, 0.f, 0.f, 0.f);
        ushort4 p;
        p.x = f2bf(hv.x); p.y = f2bf(hv.y); p.z = f2bf(hv.z); p.w = f2bf(hv.w);
        *(ushort4*)(Hl + r * LDW + k4) = p;
    }
    __syncthreads();

    const int wave  = t >> 6;
    const int lane  = t & 63;
    const int quad  = lane >> 4;
    const int l15   = lane & 15;
    const int nbase = wave * 32;

    f32x4 acc[4][2];
#pragma unroll
    for (int mt = 0; mt < 4; ++mt)
#pragma unroll
        for (int nt = 0; nt < 2; ++nt) acc[mt][nt] = (f32x4)(0.0f);

#pragma unroll
    for (int kc = 0; kc < 4; ++kc) {
        int ko = kc * 32 + quad * 8;
        bf16x8 a[4], b[2];
#pragma unroll
        for (int nt = 0; nt < 2; ++nt)
            b[nt] = *(const bf16x8*)(Wb + (size_t)(nbase + nt * 16 + l15) * D + ko);
#pragma unroll
        for (int mt = 0; mt < 4; ++mt)
            a[mt] = *(const bf16x8*)(Hl + (mt * 16 + l15) * LDW + ko);
#pragma unroll
        for (int mt = 0; mt < 4; ++mt)
#pragma unroll
            for (int nt = 0; nt < 2; ++nt)
                acc[mt][nt] = __builtin_amdgcn_mfma_f32_16x16x32_bf16(
                    a[mt], b[nt], acc[mt][nt], 0, 0, 0);
    }
    __syncthreads();

#pragma unroll
    for (int mt = 0; mt < 4; ++mt)
#pragma unroll
        for (int r = 0; r < 4; ++r) {
            int rowl = mt * 16 + quad * 4 + r;
            float dv = sdv[rowl];
#pragma unroll
            for (int nt = 0; nt < 2; ++nt)
                Hl[rowl * LDW + nbase + nt * 16 + l15] = f2bf(acc[mt][nt][r] * dv);
        }
    __syncthreads();

    for (int i = t; i < 1024; i += 256) {
        int r = i >> 4, seg = i & 15;
        int gn = gn0 + r;
        if (gn < n) {
            uint4 v = *(const uint4*)(Hl + r * LDW + seg * 8);
            *(uint4*)(xw + (size_t)gn * D + seg * 8) = v;
        }
    }
}

// ------- fused pull + bias + LN + ReLU + residual (+ next-layer GEMM) -------
// R7-proven configuration: 16 lanes/node x 16 nodes/block, 4-deep edge
// unroll (VGPR 36, occupancy ~59%). 8-deep + dual-LDS was a measured
// regression (R8: VGPR 56, occupancy 37%) — wave count beats per-wave ILP.

template <int ID_BF16, int OUT_BF16, int FUSE>
__global__ __launch_bounds__(256) void k_pull_ln(const ushort* __restrict__ xw,
                                                 const int* __restrict__ ptr,
                                                 const int2* __restrict__ csr,
                                                 const float* __restrict__ dinv,
                                                 const float* __restrict__ bias,
                                                 const float* __restrict__ gamma,
                                                 const float* __restrict__ beta,
                                                 const void* __restrict__ identity,
                                                 void* __restrict__ hout,
                                                 const ushort* __restrict__ Wn,
                                                 ushort* __restrict__ xwout,
                                                 int n, int relu) {
    __shared__ ushort Hl[16 * LDW];
    __shared__ float  sdv[16];

    const int t     = threadIdx.x;
    const int node0 = blockIdx.x * 16;
    const int g16   = t >> 4;          // node slot 0..15
    const int f     = t & 15;          // feature group
    const int o     = f * 8;           // 8 bf16 features = 16B
    const int node  = node0 + g16;
    const bool act  = node < n;

    float a0 = 0.f, a1 = 0.f, a2 = 0.f, a3 = 0.f;
    float a4 = 0.f, a5 = 0.f, a6 = 0.f, a7 = 0.f;

    int ebeg = act ? ptr[node] : 0;
    int eend = act ? ptr[node + 1] : 0;

#define ACC8(nw, g)                                        \
    a0 += nw * bflo(g.x); a1 += nw * bfhi(g.x);            \
    a2 += nw * bflo(g.y); a3 += nw * bfhi(g.y);            \
    a4 += nw * bflo(g.z); a5 += nw * bfhi(g.z);            \
    a6 += nw * bflo(g.w); a7 += nw * bfhi(g.w);

    int e = ebeg;
    for (; e + 3 < eend; e += 4) {
        int2 c0 = csr[e], c1 = csr[e + 1], c2 = csr[e + 2], c3 = csr[e + 3];
        uint4 g0 = *(const uint4*)(xw + (size_t)c0.x * D + o);
        uint4 g1 = *(const uint4*)(xw + (size_t)c1.x * D + o);
        uint4 g2 = *(const uint4*)(xw + (size_t)c2.x * D + o);
        uint4 g3 = *(const uint4*)(xw + (size_t)c3.x * D + o);
        float n0 = __int_as_float(c0.y), n1 = __int_as_float(c1.y);
        float n2 = __int_as_float(c2.y), n3 = __int_as_float(c3.y);
        ACC8(n0, g0)
        ACC8(n1, g1)
        ACC8(n2, g2)
        ACC8(n3, g3)
    }
    for (; e < eend; ++e) {
        int2 c0 = csr[e];
        uint4 g0 = *(const uint4*)(xw + (size_t)c0.x * D + o);
        float n0 = __int_as_float(c0.y);
        ACC8(n0, g0)
    }
#undef ACC8

    float o0 = 0.f, o1 = 0.f, o2 = 0.f, o3 = 0.f;
    float o4 = 0.f, o5 = 0.f, o6 = 0.f, o7 = 0.f;
    float di = 0.f;
    if (act) {
        di = dinv[node];
        uint4 ps = *(const uint4*)(xw + (size_t)node * D + o);
        float4 bbA = *(const float4*)(bias + o);
        float4 bbB = *(const float4*)(bias + o + 4);
        a0 = bbA.x + di * (bflo(ps.x) + a0);
        a1 = bbA.y + di * (bfhi(ps.x) + a1);
        a2 = bbA.z + di * (bflo(ps.y) + a2);
        a3 = bbA.w + di * (bfhi(ps.y) + a3);
        a4 = bbB.x + di * (bflo(ps.z) + a4);
        a5 = bbB.y + di * (bfhi(ps.z) + a5);
        a6 = bbB.z + di * (bflo(ps.w) + a6);
        a7 = bbB.w + di * (bfhi(ps.w) + a7);

        // LayerNorm over 128 features: reduce across the node's 16 lanes
        float s = ((a0 + a1) + (a2 + a3)) + ((a4 + a5) + (a6 + a7));
#pragma unroll
        for (int off = 8; off; off >>= 1) s += __shfl_xor(s, off);
        float mu = s * (1.0f / 128.0f);
        float d0 = a0 - mu, d1 = a1 - mu, d2 = a2 - mu, d3 = a3 - mu;
        float d4 = a4 - mu, d5 = a5 - mu, d6 = a6 - mu, d7 = a7 - mu;
        float vs = ((d0 * d0 + d1 * d1) + (d2 * d2 + d3 * d3))
                 + ((d4 * d4 + d5 * d5) + (d6 * d6 + d7 * d7));
#pragma unroll
        for (int off = 8; off; off >>= 1) vs += __shfl_xor(vs, off);
        float rs = rsqrtf(vs * (1.0f / 128.0f) + 1e-5f);

        float4 gA  = *(const float4*)(gamma + o);
        float4 gB  = *(const float4*)(gamma + o + 4);
        float4 b2A = *(const float4*)(beta + o);
        float4 b2B = *(const float4*)(beta + o + 4);
        float i0, i1, i2, i3, i4, i5, i6, i7;
        if (ID_BF16) {
            uint4 iv = *(const uint4*)((const ushort*)identity + (size_t)node * D + o);
            i0 = bflo(iv.x); i1 = bfhi(iv.x); i2 = bflo(iv.y); i3 = bfhi(iv.y);
            i4 = bflo(iv.z); i5 = bfhi(iv.z); i6 = bflo(iv.w); i7 = bfhi(iv.w);
        } else {
            float4 ivA = *(const float4*)((const float*)identity + (size_t)node * D + o);
            float4 ivB = *(const float4*)((const float*)identity + (size_t)node * D + o + 4);
            i0 = ivA.x; i1 = ivA.y; i2 = ivA.z; i3 = ivA.w;
            i4 = ivB.x; i5 = ivB.y; i6 = ivB.z; i7 = ivB.w;
        }
        o0 = d0 * rs * gA.x + b2A.x;
        o1 = d1 * rs * gA.y + b2A.y;
        o2 = d2 * rs * gA.z + b2A.z;
        o3 = d3 * rs * gA.w + b2A.w;
        o4 = d4 * rs * gB.x + b2B.x;
        o5 = d5 * rs * gB.y + b2B.y;
        o6 = d6 * rs * gB.z + b2B.z;
        o7 = d7 * rs * gB.w + b2B.w;
        if (relu) {
            o0 = fmaxf(o0, 0.0f); o1 = fmaxf(o1, 0.0f);
            o2 = fmaxf(o2, 0.0f); o3 = fmaxf(o3, 0.0f);
            o4 = fmaxf(o4, 0.0f); o5 = fmaxf(o5, 0.0f);
            o6 = fmaxf(o6, 0.0f); o7 = fmaxf(o7, 0.0f);
        }
        o0 += i0; o1 += i1; o2 += i2; o3 += i3;
        o4 += i4; o5 += i5; o6 += i6; o7 += i7;

        uint4 pv;
        pv.x = (uint)f2bf(o0) | ((uint)f2bf(o1) << 16);
        pv.y = (uint)f2bf(o2) | ((uint)f2bf(o3) << 16);
        pv.z = (uint)f2bf(o4) | ((uint)f2bf(o5) << 16);
        pv.w = (uint)f2bf(o6) | ((uint)f2bf(o7) << 16);
        if (OUT_BF16) {
            *(uint4*)((ushort*)hout + (size_t)node * D + o) = pv;
        } else {
            float* hp = (float*)hout + (size_t)node * D + o;
            *(float4*)hp       = make_float4(o0, o1, o2, o3);
            *(float4*)(hp + 4) = make_float4(o4, o5, o6, o7);
        }
        if (FUSE) {
            *(uint4*)(Hl + g16 * LDW + o) = pv;
            if (f == 0) sdv[g16] = di;
        }
    } else if (FUSE) {
        uint4 z = make_uint4(0u, 0u, 0u, 0u);
        *(uint4*)(Hl + g16 * LDW + o) = z;
        if (f == 0) sdv[g16] = 0.0f;
    }

    if (FUSE) {
        __syncthreads();
        const int lane = t & 63, wv = t >> 6;
        const int l15 = lane & 15, quad = lane >> 4;
        const int nbase = wv * 32;
        f32x4 acc2[2];
        acc2[0] = (f32x4)(0.0f);
        acc2[1] = (f32x4)(0.0f);
#pragma unroll
        for (int kc = 0; kc < 4; ++kc) {
            int ko = kc * 32 + quad * 8;
            bf16x8 a  = *(const bf16x8*)(Hl + l15 * LDW + ko);
            bf16x8 b0 = *(const bf16x8*)(Wn + (size_t)(nbase + l15) * D + ko);
            bf16x8 b1 = *(const bf16x8*)(Wn + (size_t)(nbase + 16 + l15) * D + ko);
            acc2[0] = __builtin_amdgcn_mfma_f32_16x16x32_bf16(a, b0, acc2[0], 0, 0, 0);
            acc2[1] = __builtin_amdgcn_mfma_f32_16x16x32_bf16(a, b1, acc2[1], 0, 0, 0);
        }
        __syncthreads();
#pragma unroll
        for (int r = 0; r < 4; ++r) {
            float dv = sdv[quad * 4 + r];
            Hl[(quad * 4 + r) * LDW + nbase + l15]      = f2bf(acc2[0][r] * dv);
            Hl[(quad * 4 + r) * LDW + nbase + 16 + l15] = f2bf(acc2[1][r] * dv);
        }
        __syncthreads();
        int row = t >> 4, seg = t & 15;
        int gn = node0 + row;
        if (gn < n) {
            *(uint4*)(xwout + (size_t)gn * D + seg * 8) =
                *(const uint4*)(Hl + row * LDW + seg * 8);
        }
    }
}

// ---------------- launch ----------------

extern "C" void kernel_launch(void* const* d_in, const int* in_sizes, int n_in,
                              void* d_out, int out_size, void* d_ws, size_t ws_size,
                              hipStream_t stream) {
    const float* x      = (const float*)d_in[0];
    const int*   ei     = (const int*)d_in[1];
    const float* ew     = (const float*)d_in[2];
    const float* Ws     = (const float*)d_in[3];
    const float* bs     = (const float*)d_in[4];
    const float* gammas = (const float*)d_in[5];
    const float* betas  = (const float*)d_in[6];
    float* out = (float*)d_out;

    const int N = in_sizes[0] / D;
    const int E = in_sizes[2];
    const int* row = ei;
    const int* col = ei + E;

    const int nbSort = (E + CHUNK - 1) / CHUNK;

    // workspace layout. recA (8B*E = 12.8MB) aliases the hb1/hb2/xwB union
    // (38.4MB): recA is dead after k_finish, before any of them is written.
    char* w8 = (char*)d_ws;
    ushort* Wb  = (ushort*)w8;  w8 += sizeof(ushort) * 3 * D * D;
    ushort* xwA = (ushort*)w8;  w8 += sizeof(ushort) * (size_t)N * D;  // layers 0,2
    size_t third = sizeof(ushort) * (size_t)N * D;                     // 12.8MB
    size_t unionBytes = 3 * third;                                     // hb1+hb2+xwB
    if (sizeof(ull) * (size_t)E > unionBytes) unionBytes = sizeof(ull) * (size_t)E;
    ull*    recA = (ull*)w8;
    ushort* hb1  = (ushort*)w8;
    ushort* hb2  = (ushort*)(w8 + third);
    ushort* xwB  = (ushort*)(w8 + 2 * third);                          // layer 1
    w8 += unionBytes;
    int2*  csr   = (int2*)w8;   w8 += sizeof(int2) * (size_t)E;
    int*   ghist = (int*)w8;    w8 += sizeof(int) * (size_t)nbSort * NBUCKET;
    int*   cpart = (int*)w8;    w8 += sizeof(int) * NCHK * NBUCKET;
    int*   gptr  = (int*)w8;    w8 += sizeof(int) * (NBUCKET + 4);
    int*   ptr   = (int*)w8;    w8 += sizeof(int) * (N + 4);
    float* dinv  = (float*)w8;  w8 += sizeof(float) * (size_t)N;

    dim3 blk(256);
    dim3 blk1k(1024);
    int gGemm = (N + 63) / 64;
    int gPull = (N + 15) / 16;
    int gWconv = (3 * D * D) / (1024 * 8);     // 6

    k_rhist<<<nbSort + gWconv, blk1k, 0, stream>>>(col, ghist, E, nbSort, Ws, Wb);
    k_rscanA<<<NCHK, blk, 0, stream>>>(ghist, cpart, nbSort);
    k_rscanBC<<<NCHK, blk, 0, stream>>>(cpart, ghist, gptr, ptr, N, E, nbSort);
    k_rscatter<<<nbSort, blk1k, 0, stream>>>(row, col, ew, ghist, recA, E);
    k_finish<<<NBUCKET, blk1k, 0, stream>>>(recA, gptr, ptr, dinv, csr, N);

    // layer 0: xwA = dinv * x@W0^T
    k_gemm0<<<gGemm, blk, 0, stream>>>(x, Wb, dinv, xwA, N);
    // pull 0: h0 -> hb1; fused gemm: xwB = dinv * h0@W1^T
    k_pull_ln<0, 1, 1><<<gPull, blk, 0, stream>>>(xwA, ptr, csr, dinv,
                                                  bs, gammas, betas, x, hb1,
                                                  Wb + 16384, xwB, N, 1);
    // pull 1: h1 -> hb2; fused gemm: xwA = dinv * h1@W2^T
    k_pull_ln<1, 1, 1><<<gPull, blk, 0, stream>>>(xwB, ptr, csr, dinv,
                                                  bs + D, gammas + D, betas + D,
                                                  hb1, hb2,
                                                  Wb + 32768, xwA, N, 1);
    // pull 2: final -> out (f32), no fusion
    k_pull_ln<1, 0, 0><<<gPull, blk, 0, stream>>>(xwA, ptr, csr, dinv,
                                                  bs + 2 * D, gammas + 2 * D,
                                                  betas + 2 * D,
                                                  hb2, out,
                                                  (const ushort*)nullptr,
                                                  (ushort*)nullptr, N, 0);
}